// Round 4
// baseline (30333.719 us; speedup 1.0000x reference)
//
#include <hip/hip_runtime.h>
#include <hip/hip_bf16.h>
#include <math.h>

// Problem config (fixed)
#define BB 32      // batch
#define TT 128     // time steps
#define UU 1024    // units
#define MM 8       // memory slots
#define LL 9       // M+1
#define RR 17      // 2M+1

typedef __bf16 bf16x8 __attribute__((ext_vector_type(8)));
typedef float f32x4 __attribute__((ext_vector_type(4)));

// exact 3-way bf16 split: v = x1 + x2 + x3 + O(2^-27 v)
__device__ __forceinline__ void split3(float v, __bf16* x1, __bf16* x2, __bf16* x3)
{
    __bf16 h1 = (__bf16)v;  float r = v - (float)h1;
    __bf16 h2 = (__bf16)r;  r -= (float)h2;
    *x1 = h1; *x2 = h2; *x3 = (__bf16)r;
}

// ---------------- split-bf16 6-term MFMA GEMM ----------------
// C[M,N] = A[M,1024] @ Bt[N,1024]^T (+bias,+act), A,B given as 3 bf16 planes.
// 4 waves/block in 2x2: each wave 16 rows x (CG*16) cols.
// grid = (N/(2*CG*16), M/32). M%32==0.
template<int CG>
__global__ __launch_bounds__(256) void gemm_split6(
    const __bf16* __restrict__ A1, const __bf16* __restrict__ A2,
    const __bf16* __restrict__ A3,
    const __bf16* __restrict__ B1, const __bf16* __restrict__ B2,
    const __bf16* __restrict__ B3,
    const float* __restrict__ bias,
    float* __restrict__ Cf,                       // optional fp32 out
    __bf16* __restrict__ P1, __bf16* __restrict__ P2, __bf16* __restrict__ P3,
    int ldc, int act)                             // planes use ldc too (==1024)
{
    constexpr int K = 1024;
    int wave = threadIdx.x >> 6, lane = threadIdx.x & 63;
    int row0 = blockIdx.y * 32 + (wave >> 1) * 16;
    int col0 = (blockIdx.x * 2 + (wave & 1)) * (CG * 16);
    int lr = lane & 15, kofs = (lane >> 4) * 8;

    const __bf16* a1p = A1 + (size_t)(row0 + lr) * K + kofs;
    const __bf16* a2p = A2 + (size_t)(row0 + lr) * K + kofs;
    const __bf16* a3p = A3 + (size_t)(row0 + lr) * K + kofs;
    size_t boff = (size_t)(col0 + lr) * K + kofs;

    f32x4 acc[CG];
#pragma unroll
    for (int c = 0; c < CG; ++c) acc[c] = (f32x4){0.f, 0.f, 0.f, 0.f};

    for (int k = 0; k < K; k += 32) {
        bf16x8 a1 = *(const bf16x8*)(a1p + k);
        bf16x8 a2 = *(const bf16x8*)(a2p + k);
        bf16x8 a3 = *(const bf16x8*)(a3p + k);
#pragma unroll
        for (int c = 0; c < CG; ++c) {
            size_t o = boff + (size_t)c * 16 * K + k;
            bf16x8 b1 = *(const bf16x8*)(B1 + o);
            bf16x8 b2 = *(const bf16x8*)(B2 + o);
            bf16x8 b3 = *(const bf16x8*)(B3 + o);
            acc[c] = __builtin_amdgcn_mfma_f32_16x16x32_bf16(a1, b1, acc[c], 0, 0, 0);
            acc[c] = __builtin_amdgcn_mfma_f32_16x16x32_bf16(a1, b2, acc[c], 0, 0, 0);
            acc[c] = __builtin_amdgcn_mfma_f32_16x16x32_bf16(a2, b1, acc[c], 0, 0, 0);
            acc[c] = __builtin_amdgcn_mfma_f32_16x16x32_bf16(a1, b3, acc[c], 0, 0, 0);
            acc[c] = __builtin_amdgcn_mfma_f32_16x16x32_bf16(a2, b2, acc[c], 0, 0, 0);
            acc[c] = __builtin_amdgcn_mfma_f32_16x16x32_bf16(a3, b1, acc[c], 0, 0, 0);
        }
    }

    int r0 = row0 + (lane >> 4) * 4;
#pragma unroll
    for (int c = 0; c < CG; ++c) {
        int col = col0 + c * 16 + lr;
        float bv = bias ? bias[col] : 0.f;
#pragma unroll
        for (int r = 0; r < 4; ++r) {
            float v = acc[c][r] + bv;
            if (act == 1) {  // gelu (tanh approx, JAX default)
                float x = v;
                float t = tanhf(0.7978845608028654f * (x + 0.044715f * x * x * x));
                v = 0.5f * x * (1.f + t);
            }
            size_t off = (size_t)(r0 + r) * ldc + col;
            if (Cf) Cf[off] = v;
            if (P1) split3(v, P1 + off, P2 + off, P3 + off);
        }
    }
}

// ---------------- big fp32 GEMM (one-time prep: xp, gx) ----------------
__global__ __launch_bounds__(256) void gemm_big(
    const float* __restrict__ A, const float* __restrict__ B,
    const float* __restrict__ bias, float* __restrict__ C,
    int M, int N, int K, int act)
{
    __shared__ float As[64][68];
    __shared__ float Bs[64][128];
    int tid = threadIdx.x;
    int row0 = blockIdx.y * 64, colB = blockIdx.x * 128;
    int ty = tid >> 5, tx = tid & 31;
    float acc[8][4];
#pragma unroll
    for (int i = 0; i < 8; ++i)
#pragma unroll
        for (int j = 0; j < 4; ++j) acc[i][j] = 0.f;

    for (int k0 = 0; k0 < K; k0 += 64) {
#pragma unroll
        for (int p = 0; p < 4; ++p) {
            int r = p * 16 + (tid >> 4);
            int kv = (tid & 15) * 4;
            *(float4*)&As[r][kv] =
                *(const float4*)(A + (size_t)(row0 + r) * K + k0 + kv);
        }
#pragma unroll
        for (int p = 0; p < 8; ++p) {
            int r = p * 8 + (tid >> 5);
            int c = (tid & 31) * 4;
            *(float4*)&Bs[r][c] = *(const float4*)(B + (size_t)(k0 + r) * N + colB + c);
        }
        __syncthreads();
#pragma unroll 8
        for (int kk = 0; kk < 64; ++kk) {
            float b0[4];
            *(float4*)b0 = *(const float4*)&Bs[kk][tx * 4];
            float a0[8];
#pragma unroll
            for (int i = 0; i < 8; ++i) a0[i] = As[ty * 8 + i][kk];
#pragma unroll
            for (int i = 0; i < 8; ++i)
#pragma unroll
                for (int j = 0; j < 4; ++j) acc[i][j] += a0[i] * b0[j];
        }
        __syncthreads();
    }
#pragma unroll
    for (int i = 0; i < 8; ++i) {
        int gr = row0 + ty * 8 + i;
#pragma unroll
        for (int j = 0; j < 4; ++j) {
            float v = acc[i][j];
            if (bias) v += bias[colB + tx * 4 + j];
            C[(size_t)gr * N + colB + tx * 4 + j] = v;
        }
    }
}

// ---------------- tiny fp32 GEMM (rproj) ----------------
#define BKK 16
__global__ __launch_bounds__(256) void gemm_f32(
    const float* __restrict__ A, const float* __restrict__ B,
    float* __restrict__ C, int M, int N, int K)
{
    __shared__ float As[BKK][65];
    __shared__ float Bs[BKK][64];
    int tid = threadIdx.x;
    int row0 = blockIdx.y * 64, col0 = blockIdx.x * 64;
    int ty = tid >> 4, tx = tid & 15;
    float acc[4][4];
#pragma unroll
    for (int i = 0; i < 4; ++i)
#pragma unroll
        for (int j = 0; j < 4; ++j) acc[i][j] = 0.f;
    for (int k0 = 0; k0 < K; k0 += BKK) {
        {
            int r = tid >> 2, kv = (tid & 3) * 4;
            float4 v = make_float4(0.f, 0.f, 0.f, 0.f);
            int gr = row0 + r;
            if (gr < M) v = *(const float4*)(A + (size_t)gr * K + k0 + kv);
            As[kv + 0][r] = v.x; As[kv + 1][r] = v.y;
            As[kv + 2][r] = v.z; As[kv + 3][r] = v.w;
        }
        {
            int r = tid >> 4, cv = (tid & 15) * 4;
            float4 v = *(const float4*)(B + (size_t)(k0 + r) * N + col0 + cv);
            *(float4*)&Bs[r][cv] = v;
        }
        __syncthreads();
#pragma unroll
        for (int kk = 0; kk < BKK; ++kk) {
            float a[4], b[4];
#pragma unroll
            for (int j = 0; j < 4; ++j) a[j] = As[kk][ty * 4 + j];
#pragma unroll
            for (int j = 0; j < 4; ++j) b[j] = Bs[kk][tx * 4 + j];
#pragma unroll
            for (int i = 0; i < 4; ++i)
#pragma unroll
                for (int j = 0; j < 4; ++j) acc[i][j] += a[i] * b[j];
        }
        __syncthreads();
    }
#pragma unroll
    for (int i = 0; i < 4; ++i) {
        int gr = row0 + ty * 4 + i;
        if (gr >= M) continue;
#pragma unroll
        for (int j = 0; j < 4; ++j)
            C[(size_t)gr * N + col0 + tx * 4 + j] = acc[i][j];
    }
}

// ---------- weight transpose + 3-way split: out[N,1024] planes = in[1024,N]^T
__global__ __launch_bounds__(256) void transpose_split(
    const float* __restrict__ in,
    __bf16* __restrict__ o1, __bf16* __restrict__ o2, __bf16* __restrict__ o3,
    int N)
{
    __shared__ float t[32][33];
    int tx = threadIdx.x & 31, ty = threadIdx.x >> 5;
    int k0 = blockIdx.y * 32, n0 = blockIdx.x * 32;
#pragma unroll
    for (int i = 0; i < 4; ++i)
        t[ty + i * 8][tx] = in[(size_t)(k0 + ty + i * 8) * N + n0 + tx];
    __syncthreads();
#pragma unroll
    for (int i = 0; i < 4; ++i) {
        float v = t[tx][ty + i * 8];
        size_t off = (size_t)(n0 + ty + i * 8) * 1024 + k0 + tx;
        split3(v, o1 + off, o2 + off, o3 + off);
    }
}

// ---------------- relative embedding table ----------------
__global__ void relemb_kernel(float* __restrict__ tab)
{
    int p = blockIdx.x;
    float pv = (float)(p - MM);
    for (int i = threadIdx.x; i < UU; i += blockDim.x) {
        float expo = (float)(i & ~1) * (1.0f / (float)UU);
        float scale = exp2f(-expo * 13.287712379549449f);  // 10000^-expo
        float ang = pv * scale;
        tab[p * UU + i] = (i & 1) ? cosf(ang) : sinf(ang);
    }
}

// ---------------- init mp (+ split planes) ----------------
__global__ void init_mp(const float* __restrict__ xp_all, float* __restrict__ mp,
                        __bf16* __restrict__ p1, __bf16* __restrict__ p2,
                        __bf16* __restrict__ p3)
{
    int row = blockIdx.x;                 // 0..287
    int b = row / LL, l = row % LL;
    for (int u = threadIdx.x; u < UU; u += blockDim.x) {
        float v = (l == MM) ? xp_all[((size_t)b * TT) * UU + u] : 0.f;
        size_t off = (size_t)row * UU + u;
        mp[off] = v;
        split3(v, p1 + off, p2 + off, p3 + off);
    }
}

// ---------------- attention + LN1 (+ a1 split planes) ----------------
__global__ __launch_bounds__(512) void attn_ln(
    const float* __restrict__ qkvg, const float* __restrict__ rproj,
    const float* __restrict__ mp,
    const float* __restrict__ gamma, const float* __restrict__ beta,
    float* __restrict__ a1,
    __bf16* __restrict__ p1, __bf16* __restrict__ p2, __bf16* __restrict__ p3)
{
    __shared__ float sA[LL][UU];
    __shared__ float red[16];
    int b = blockIdx.x;
    int tid = threadIdx.x;
    int wave = tid >> 6, lane = tid & 63;

    for (int hh = 0; hh < 2; ++hh) {
        int h = wave + hh * 8;
        const float* base = qkvg + (size_t)b * LL * 5120 + h * 64 + lane;
        float q[LL], k[LL], v[LL], r[RR];
#pragma unroll
        for (int l = 0; l < LL; ++l) {
            q[l] = base[l * 5120];
            k[l] = base[l * 5120 + 1024];
            v[l] = base[l * 5120 + 2048];
        }
#pragma unroll
        for (int rp = 0; rp < RR; ++rp) r[rp] = rproj[rp * UU + h * 64 + lane];
#pragma unroll
        for (int qr = 0; qr < LL; ++qr) {
            float sc[LL];
#pragma unroll
            for (int kr = 0; kr < LL; ++kr) {
                float prod = q[qr] * (k[kr] + r[qr - kr + MM]);
#pragma unroll
                for (int o = 32; o > 0; o >>= 1) prod += __shfl_xor(prod, o);
                sc[kr] = prod * 0.125f;
            }
            float m = sc[0];
#pragma unroll
            for (int kr = 1; kr < LL; ++kr) m = fmaxf(m, sc[kr]);
            float s = 0.f;
#pragma unroll
            for (int kr = 0; kr < LL; ++kr) { sc[kr] = expf(sc[kr] - m); s += sc[kr]; }
            float inv = 1.0f / s;
            float acc = 0.f;
#pragma unroll
            for (int kr = 0; kr < LL; ++kr) acc += sc[kr] * v[kr];
            sA[qr][h * 64 + lane] = acc * inv;
        }
    }
    __syncthreads();

    for (int l = 0; l < LL; ++l) {
        size_t row = (size_t)(b * LL + l);
        float x0 = mp[row * UU + tid] + sA[l][tid];
        float x1 = mp[row * UU + tid + 512] + sA[l][tid + 512];
        float s = x0 + x1, ss = x0 * x0 + x1 * x1;
#pragma unroll
        for (int o = 32; o > 0; o >>= 1) { s += __shfl_xor(s, o); ss += __shfl_xor(ss, o); }
        if (lane == 0) { red[wave * 2] = s; red[wave * 2 + 1] = ss; }
        __syncthreads();
        float S = 0.f, SS = 0.f;
#pragma unroll
        for (int w = 0; w < 8; ++w) { S += red[w * 2]; SS += red[w * 2 + 1]; }
        __syncthreads();
        float mean = S * (1.0f / UU);
        float var = SS * (1.0f / UU) - mean * mean;
        float rstd = rsqrtf(var + 1e-6f);
        float v0 = (x0 - mean) * rstd * gamma[tid] + beta[tid];
        float v1 = (x1 - mean) * rstd * gamma[tid + 512] + beta[tid + 512];
        a1[row * UU + tid] = v0;
        a1[row * UU + tid + 512] = v1;
        split3(v0, p1 + row * UU + tid, p2 + row * UU + tid, p3 + row * UU + tid);
        split3(v1, p1 + row * UU + tid + 512, p2 + row * UU + tid + 512,
               p3 + row * UU + tid + 512);
    }
}

// ---------------- finalize: LN2 + gates + memory update (+ mp splits) --------
__global__ __launch_bounds__(256) void finalize_step(
    const float* __restrict__ a1, const float* __restrict__ m2,
    const float* __restrict__ qkvg, const float* __restrict__ gx_all,
    const float* __restrict__ xp_all,
    const float* __restrict__ gamma, const float* __restrict__ beta,
    float* __restrict__ mp,
    __bf16* __restrict__ p1, __bf16* __restrict__ p2, __bf16* __restrict__ p3,
    float* __restrict__ out, int t)
{
    __shared__ float red[8];
    int row = blockIdx.x;                 // 0..287
    int b = row / LL, l = row % LL;
    int tid = threadIdx.x;
    int wave = tid >> 6, lane = tid & 63;

    float x[4];
    float s = 0.f, ss = 0.f;
#pragma unroll
    for (int j = 0; j < 4; ++j) {
        int u = tid + j * 64 * 4;
        x[j] = a1[(size_t)row * UU + u] + m2[(size_t)row * UU + u];
        s += x[j]; ss += x[j] * x[j];
    }
#pragma unroll
    for (int o = 32; o > 0; o >>= 1) { s += __shfl_xor(s, o); ss += __shfl_xor(ss, o); }
    if (lane == 0) { red[wave * 2] = s; red[wave * 2 + 1] = ss; }
    __syncthreads();
    float S = 0.f, SS = 0.f;
#pragma unroll
    for (int w = 0; w < 4; ++w) { S += red[w * 2]; SS += red[w * 2 + 1]; }
    float mean = S * (1.0f / UU);
    float rstd = rsqrtf(SS * (1.0f / UU) - mean * mean + 1e-6f);

    size_t gxoff = ((size_t)b * TT + t) * 2048;
    size_t grow = (size_t)row * 5120 + 3072;
#pragma unroll
    for (int j = 0; j < 4; ++j) {
        int u = tid + j * 256;
        float cand = (x[j] - mean) * rstd * gamma[1024 + u] + beta[1024 + u];
        float tc = tanhf(cand);
        float gi = gx_all[gxoff + u]        + qkvg[grow + u];
        float gf = gx_all[gxoff + 1024 + u] + qkvg[grow + 1024 + u];
        float ig = fminf(fmaxf(0.2f * gi + 0.5f, 0.f), 1.f);
        float fg = fminf(fmaxf(0.2f * (gf + 1.0f) + 0.5f, 0.f), 1.f);
        size_t off = (size_t)row * UU + u;
        float nmp = fg * mp[off] + ig * tc;
        if (l < MM) {
            mp[off] = nmp;
            split3(nmp, p1 + off, p2 + off, p3 + off);
        } else {
            out[((size_t)b * TT + t) * UU + u] = nmp;
            if (t + 1 < TT) {
                float nx = xp_all[((size_t)b * TT + t + 1) * UU + u];
                mp[off] = nx;
                split3(nx, p1 + off, p2 + off, p3 + off);
            }
        }
    }
}

// ---------------- host launcher ----------------
extern "C" void kernel_launch(void* const* d_in, const int* in_sizes, int n_in,
                              void* d_out, int out_size, void* d_ws, size_t ws_size,
                              hipStream_t stream)
{
    const float* x    = (const float*)d_in[0];   // [32,128,1024]
    const float* Wi   = (const float*)d_in[1];   // [1024,1024]
    const float* bi   = (const float*)d_in[2];   // [1024]
    const float* Wg   = (const float*)d_in[3];   // [1024,2048]
    const float* Wr   = (const float*)d_in[4];   // [1024,2048]
    const float* br   = (const float*)d_in[5];   // [2048]
    const float* Wa   = (const float*)d_in[6];   // [1024,3072]
    const float* ba   = (const float*)d_in[7];   // [3072]
    const float* Wm   = (const float*)d_in[8];   // [1024,2048]
    const float* bm   = (const float*)d_in[9];   // [2048]
    const float* gam  = (const float*)d_in[10];  // [2048]
    const float* bet  = (const float*)d_in[11];  // [2048]
    const float* Wrel = (const float*)d_in[12];  // [1024,1024]
    float* out = (float*)d_out;

    // ---- workspace layout (bytes) ----
    char* w = (char*)d_ws;
    float*  xp_all = (float*)w;  w += (size_t)BB*TT*UU*4;        // 16.8 MB
    float*  gx_all = (float*)w;  w += (size_t)BB*TT*2048*4;      // 33.6 MB
    size_t W1N = 5120 * 1024, WMN = 2048 * 1024, PN = (size_t)BB*LL*UU;
    __bf16* W1a = (__bf16*)w;    w += W1N*2;                     // 10.5 MB x3
    __bf16* W1b = (__bf16*)w;    w += W1N*2;
    __bf16* W1c = (__bf16*)w;    w += W1N*2;
    __bf16* Wma = (__bf16*)w;    w += WMN*2;                     // 4.2 MB x3
    __bf16* Wmb = (__bf16*)w;    w += WMN*2;
    __bf16* Wmc = (__bf16*)w;    w += WMN*2;
    float*  b1    = (float*)w;   w += 5120*4;
    float*  tab   = (float*)w;   w += RR*UU*4;
    float*  rproj = (float*)w;   w += RR*UU*4;
    float*  mp    = (float*)w;   w += PN*4;
    __bf16* mp1   = (__bf16*)w;  w += PN*2;
    __bf16* mp2   = (__bf16*)w;  w += PN*2;
    __bf16* mp3   = (__bf16*)w;  w += PN*2;
    float*  qkvg  = (float*)w;   w += (size_t)BB*LL*5120*4;      // 5.9 MB
    float*  a1    = (float*)w;   w += PN*4;
    __bf16* a1a   = (__bf16*)w;  w += PN*2;
    __bf16* a1b   = (__bf16*)w;  w += PN*2;
    __bf16* a1c   = (__bf16*)w;  w += PN*2;
    __bf16* h1    = (__bf16*)w;  w += PN*2;
    __bf16* h2    = (__bf16*)w;  w += PN*2;
    __bf16* h3    = (__bf16*)w;  w += PN*2;
    float*  m2    = (float*)w;   w += PN*4;

    // ---- one-time prep ----
    relemb_kernel<<<RR, 256, 0, stream>>>(tab);
    gemm_f32<<<dim3(UU / 64, 1), 256, 0, stream>>>(tab, Wrel, rproj, RR, UU, UU);
    // weight transpose+split: W1 = [Wa | Wr] -> [5120,1024] planes
    transpose_split<<<dim3(3072 / 32, 32), 256, 0, stream>>>(Wa, W1a, W1b, W1c, 3072);
    transpose_split<<<dim3(2048 / 32, 32), 256, 0, stream>>>(
        Wr, W1a + (size_t)3072 * 1024, W1b + (size_t)3072 * 1024,
        W1c + (size_t)3072 * 1024, 2048);
    transpose_split<<<dim3(2048 / 32, 32), 256, 0, stream>>>(Wm, Wma, Wmb, Wmc, 2048);
    hipMemcpyAsync(b1, ba, 3072 * sizeof(float), hipMemcpyDeviceToDevice, stream);
    hipMemcpyAsync(b1 + 3072, br, 2048 * sizeof(float), hipMemcpyDeviceToDevice, stream);
    // xp_all = x @ Wi + bi ; gx_all = x @ Wg  (one-time, fp32)
    gemm_big<<<dim3(UU / 128, (BB * TT) / 64), 256, 0, stream>>>(
        x, Wi, bi, xp_all, BB * TT, UU, UU, 0);
    gemm_big<<<dim3(2048 / 128, (BB * TT) / 64), 256, 0, stream>>>(
        x, Wg, nullptr, gx_all, BB * TT, 2048, UU, 0);
    init_mp<<<BB * LL, 256, 0, stream>>>(xp_all, mp, mp1, mp2, mp3);

    // ---- sequential scan ----
    for (int t = 0; t < TT; ++t) {
        // qkvg[288,5120] = mp @ [Wa|Wr] + [ba|br]   (split6 MFMA)
        gemm_split6<4><<<dim3(5120 / 128, (BB * LL) / 32), 256, 0, stream>>>(
            mp1, mp2, mp3, W1a, W1b, W1c, b1, qkvg,
            nullptr, nullptr, nullptr, 5120, 0);
        attn_ln<<<BB, 512, 0, stream>>>(qkvg, rproj, mp, gam, bet, a1, a1a, a1b, a1c);
        // h = gelu(a1 @ Wm[:,:U] + bm[:U]) -> split planes only
        gemm_split6<2><<<dim3(UU / 64, (BB * LL) / 32), 256, 0, stream>>>(
            a1a, a1b, a1c, Wma, Wmb, Wmc, bm, nullptr, h1, h2, h3, UU, 1);
        // m2 = h @ Wm[:,U:] + bm[U:]
        gemm_split6<2><<<dim3(UU / 64, (BB * LL) / 32), 256, 0, stream>>>(
            h1, h2, h3, Wma + (size_t)1024 * 1024, Wmb + (size_t)1024 * 1024,
            Wmc + (size_t)1024 * 1024, bm + 1024, m2, nullptr, nullptr, nullptr, UU, 0);
        finalize_step<<<BB * LL, 256, 0, stream>>>(a1, m2, qkvg, gx_all, xp_all,
                                                   gam, bet, mp, mp1, mp2, mp3, out, t);
    }
}